// Round 15
// baseline (663.022 us; speedup 1.0000x reference)
//
#include <hip/hip_runtime.h>
#include <math.h>

#define NN 100000
#define NE 1600000
#define DD 32
#define CC 16
#define SCAN_B 391    // ceil(NN/256)
#define NT 6250       // node tiles (NN/16, exact)
#define NB2 (NE / 16) // 100000 edge blocks (16 edges each), exact

typedef unsigned short bf16_t;
typedef __attribute__((ext_vector_type(8))) short short8v;
typedef __attribute__((ext_vector_type(4))) float float4v;

static inline unsigned gblocks(long total) { return (unsigned)((total + 255) / 256); }

__device__ inline bf16_t f2bf(float f) {
    unsigned u = __float_as_uint(f);
    u += 0x7fffu + ((u >> 16) & 1u);
    return (bf16_t)(u >> 16);
}
__device__ inline float bf2f(bf16_t h) { return __uint_as_float(((unsigned)h) << 16); }
__device__ inline unsigned pk2(float a, float b) {
    return (unsigned)f2bf(a) | ((unsigned)f2bf(b) << 16);
}

__global__ void zero_k(float* p, long n) {
    long i = (long)blockIdx.x * 256 + threadIdx.x;
    if (i < n) p[i] = 0.f;
}
__global__ void zero_int_k(int* p, int n) {
    int i = blockIdx.x * 256 + threadIdx.x;
    if (i < n) p[i] = 0;
}

// ---------------- CSR build ----------------
__global__ void hist_k(const int* __restrict__ dst, int* __restrict__ cnt) {
    int e = blockIdx.x * 256 + threadIdx.x;
    if (e < NE) atomicAdd(&cnt[dst[e]], 1);
}
__global__ void s1_k(const int* __restrict__ cnt, int* __restrict__ offs,
                     int* __restrict__ bsum) {
    __shared__ int sm[256];
    int t = threadIdx.x, b = blockIdx.x;
    int g = b * 256 + t;
    int v = (g < NN) ? cnt[g] : 0;
    sm[t] = v;
    __syncthreads();
    for (int o = 1; o < 256; o <<= 1) {
        int u = (t >= o) ? sm[t - o] : 0;
        __syncthreads();
        sm[t] += u;
        __syncthreads();
    }
    if (g < NN) offs[g + 1] = sm[t];
    if (t == 255) bsum[b] = sm[255];
}
__global__ void s2_k(int* __restrict__ bsum) {
    __shared__ int sm[512];
    int t = threadIdx.x;
    int v = (t < SCAN_B) ? bsum[t] : 0;
    sm[t] = v;
    __syncthreads();
    for (int o = 1; o < 512; o <<= 1) {
        int u = (t >= o) ? sm[t - o] : 0;
        __syncthreads();
        sm[t] += u;
        __syncthreads();
    }
    if (t < SCAN_B) bsum[t] = sm[t] - v;  // exclusive
}
// fused: add block prefixes + init cur = final offs
__global__ void s3c_k(int* __restrict__ offs, const int* __restrict__ bsum,
                      int* __restrict__ cur) {
    int t = threadIdx.x, b = blockIdx.x;
    int g = b * 256 + t;
    if (g < NN) {
        int v = offs[g + 1] + bsum[b];
        offs[g + 1] = v;
        if (g + 1 < NN) cur[g + 1] = v;
    }
    if (g == 0) { offs[0] = 0; cur[0] = 0; }
}

// fill dst-sorted stream: emeta = {src[16:0] | dst[14:0]<<17,
//                                  q0[14:0] | q1[14:0]<<15 | dst[16:15]<<30}
__global__ void fill_k(const int* __restrict__ dst, const int* __restrict__ src,
                       const float2* __restrict__ attr, int* __restrict__ cur,
                       uint2* __restrict__ emeta) {
    int e = blockIdx.x * 256 + threadIdx.x;
    if (e < NE) {
        int d = dst[e];
        int pos = atomicAdd(&cur[d], 1);
        float2 uv = attr[e];
        unsigned q0 = (unsigned)(uv.x * 32767.f + 0.5f);
        unsigned q1 = (unsigned)(uv.y * 32767.f + 0.5f);
        uint2 m;
        m.x = (unsigned)src[e] | ((unsigned)(d & 0x7FFF) << 17);
        m.y = q0 | (q1 << 15) | ((unsigned)(d >> 15) << 30);
        emeta[pos] = m;
    }
}

// both weight packs in one launch
__global__ void castw2_k(const float* __restrict__ W1, const float* __restrict__ W2,
                         bf16_t* __restrict__ wtf1, bf16_t* __restrict__ wtf2) {
    int tid = blockIdx.x * 256 + threadIdx.x;
    const float* W; bf16_t* wtf; int loc;
    if (tid < 9 * 2 * 64) { W = W1; wtf = wtf1; loc = tid; }
    else if (tid < (9 + 25) * 2 * 64) { W = W2; wtf = wtf2; loc = tid - 9 * 2 * 64; }
    else return;
    int l = loc & 63;
    int half = (loc >> 6) & 1;
    int k = loc >> 7;
    int e = (l & 15) + 16 * half;
    int dbase = (l >> 4) * 8;
    bf16_t* op = wtf + (long)loc * 8;
#pragma unroll
    for (int r = 0; r < 8; ++r)
        op[r] = f2bf(W[(long)k * 1024 + (dbase + r) * DD + e]);
}

// y[n][k][d] = x[n,:] @ W[k]; 4 tiles/block (occupancy), direct reg->global
// stores.  CASTF: read f32 x directly and pack B-fragments in-register
// (fuses the castx pass for layer 1).
template<int K, bool CASTF>
__global__ __launch_bounds__(256) void ymm_k(const void* __restrict__ xsrc,
                                             const short8v* __restrict__ wtf,
                                             uint2* __restrict__ y) {
    const int tid = threadIdx.x;
    const int l = tid & 63;
    const int tile = blockIdx.x * 4 + (tid >> 6);
    if (tile >= NT) return;
    const int node = l & 15, g = l >> 4;

    short8v b;
    if (CASTF) {
        const float* xf = (const float*)xsrc;
        const float4* xp = (const float4*)(xf + ((long)tile * 16 + node) * DD + g * 8);
        float4 v0 = xp[0], v1 = xp[1];
        unsigned u[4] = { pk2(v0.x, v0.y), pk2(v0.z, v0.w),
                          pk2(v1.x, v1.y), pk2(v1.z, v1.w) };
        b = *(short8v*)u;
    } else {
        b = ((const short8v*)xsrc)[(long)tile * 64 + l];
    }

    float4v zz = {0.f, 0.f, 0.f, 0.f};
    const long nb = ((long)tile * 16 + node) * K;

    for (int k = 0; k < K; ++k) {
        float4v d0 = __builtin_amdgcn_mfma_f32_16x16x32_bf16(wtf[(2 * k + 0) * 64 + l], b, zz, 0, 0, 0);
        float4v d1 = __builtin_amdgcn_mfma_f32_16x16x32_bf16(wtf[(2 * k + 1) * 64 + l], b, zz, 0, 0, 0);
        uint2 s0, s1;
        s0.x = pk2(d0[0], d0[1]); s0.y = pk2(d0[2], d0[3]);
        s1.x = pk2(d1[0], d1[1]); s1.y = pk2(d1[2], d1[3]);
        y[(nb + k) * 8 + g] = s0;        // e = g*4 .. g*4+3
        y[(nb + k) * 8 + 4 + g] = s1;    // e = 16 + g*4 ..
    }
}

// ---------------- sorted edge phase: 16 edges/block, segmented reduce ----------------
template<int KS>
__global__ __launch_bounds__(512) void edge_sr_k(
        const uint2* __restrict__ emeta, const unsigned* __restrict__ yu,
        float* __restrict__ agg) {
    constexpr int K = KS * KS;
    __shared__ float smf[16][36];
    __shared__ int sdst[16];
    const int tid = threadIdx.x;
    const int lane = tid & 31, g = tid >> 5;
    const int al = lane & 15, half = lane >> 4;
    const int j = blockIdx.x * 16 + g;

    uint2 em = emeta[j];
    int s = (int)(em.x & 0x1FFFFu);
    int n = (int)((em.x >> 17) & 0x7FFFu) | ((int)((em.y >> 30) & 3u) << 15);
    float u0 = (float)(em.y & 0x7FFFu) * (1.f / 32767.f);
    float u1 = (float)((em.y >> 15) & 0x7FFFu) * (1.f / 32767.f);
    float v0 = u0 * (KS - 1), v1 = u1 * (KS - 1);
    int i0 = min((int)v0, KS - 2), i1 = min((int)v1, KS - 2);
    float f0 = v0 - (float)i0, f1 = v1 - (float)i1;

    float wh = half ? f0 : (1.f - f0);
    long base = ((long)s * K + i1 * KS + i0 + half) * 16 + al;
    unsigned uA = yu[base];             // plane i1, row (i0+half)
    unsigned uB = yu[base + KS * 16];   // plane i1+1
    float wA = wh * (1.f - f1), wB = wh * f1;
    float p0 = wA * bf2f((bf16_t)(uA & 0xffffu)) + wB * bf2f((bf16_t)(uB & 0xffffu));
    float p1 = wA * bf2f((bf16_t)(uA >> 16)) + wB * bf2f((bf16_t)(uB >> 16));
    p0 += __shfl_xor(p0, 16);   // combine rows i0, i0+1
    p1 += __shfl_xor(p1, 16);

    if (half == 0) {
        smf[g][2 * al] = p0;
        smf[g][2 * al + 1] = p1;
    }
    if (lane == 0) sdst[g] = n;
    __syncthreads();

    bool leader = (g == 0) || (sdst[g - 1] != n);
    if (leader) {
        float acc = smf[g][lane];
#pragma unroll
        for (int gg = 1; gg < 16; ++gg) {
            int g2 = g + gg;
            if (g2 >= 16 || sdst[g2] != n) break;
            acc += smf[g2][lane];
        }
        atomicAdd(&agg[(long)n * DD + lane], acc);
    }
}

// finalize layer 1: h1 -> bf16 fragments; re-zero agg for layer 2
__global__ __launch_bounds__(256) void fin1_k(
        float* __restrict__ agg, const int* __restrict__ offs,
        const float* __restrict__ xin, const float* __restrict__ root,
        const float* __restrict__ bias, bf16_t* __restrict__ xtf) {
    const int lane = threadIdx.x & 31;
    const int grp = threadIdx.x >> 5;
    const int n = blockIdx.x * 8 + grp;
    if (n >= NN) return;
    int deg = offs[n + 1] - offs[n];
    float c = deg > 0 ? (float)deg : 1.f;
    float xv = xin[(long)n * DD + lane];
    float racc = 0.f;
#pragma unroll
    for (int d = 0; d < DD; ++d)
        racc = fmaf(__shfl(xv, d, 32), root[d * DD + lane], racc);
    float v = agg[(long)n * DD + lane] / c + racc + bias[lane];
    agg[(long)n * DD + lane] = 0.f;
    v = v > 0.f ? v : expm1f(v);
    xtf[((long)(n >> 4) * 64 + (n & 15) + 16 * (lane >> 3)) * 8 + (lane & 7)] = f2bf(v);
}

// fused: layer-2 finalize + 2-layer MLP head -> out
__global__ __launch_bounds__(256) void finmlp_k(
        const float* __restrict__ agg, const int* __restrict__ offs,
        const bf16_t* __restrict__ xtf, const float* __restrict__ root,
        const float* __restrict__ bias, const float* __restrict__ w1,
        const float* __restrict__ b1, const float* __restrict__ w2,
        const float* __restrict__ b2, float* __restrict__ out) {
    const int lane = threadIdx.x & 31;
    const int grp = threadIdx.x >> 5;
    const int n = blockIdx.x * 8 + grp;
    if (n >= NN) return;
    int deg = offs[n + 1] - offs[n];
    float c = deg > 0 ? (float)deg : 1.f;
    float h1 = bf2f(xtf[((long)(n >> 4) * 64 + (n & 15) + 16 * (lane >> 3)) * 8 + (lane & 7)]);
    float racc = 0.f;
#pragma unroll
    for (int d = 0; d < DD; ++d)
        racc = fmaf(__shfl(h1, d, 32), root[d * DD + lane], racc);
    float h2 = agg[(long)n * DD + lane] / c + racc + bias[lane];
    h2 = h2 > 0.f ? h2 : expm1f(h2);
    float t = b1[lane];
#pragma unroll
    for (int d = 0; d < DD; ++d)
        t = fmaf(__shfl(h2, d, 32), w1[d * DD + lane], t);
    t = fmaxf(t, 0.f);
    int cc = lane & (CC - 1);
    float o = 0.f;
#pragma unroll
    for (int d = 0; d < DD; ++d)
        o = fmaf(__shfl(t, d, 32), w2[d * CC + cc], o);
    o += b2[cc];
    o = fmaxf(o, 0.f);
    if (lane < CC) out[(long)n * CC + lane] = o;
}

extern "C" void kernel_launch(void* const* d_in, const int* in_sizes, int n_in,
                              void* d_out, int out_size, void* d_ws, size_t ws_size,
                              hipStream_t stream) {
    const float* x     = (const float*)d_in[0];
    const int*   ei    = (const int*)d_in[1];
    const float* attr  = (const float*)d_in[2];
    const float* W1    = (const float*)d_in[3];
    const float* root1 = (const float*)d_in[4];
    const float* bias1 = (const float*)d_in[5];
    const float* W2    = (const float*)d_in[6];
    const float* root2 = (const float*)d_in[7];
    const float* bias2 = (const float*)d_in[8];
    const float* m1w   = (const float*)d_in[9];
    const float* m1b   = (const float*)d_in[10];
    const float* m2w   = (const float*)d_in[11];
    const float* m2b   = (const float*)d_in[12];
    float* out = (float*)d_out;

    const int* srcp = ei;
    const int* dstp = ei + NE;

    // ws: offs(NN+8) | emeta(NE uint2) | xtf(NN*32 bf16) | wtf1 | wtf2
    //     | y(NN*25*32 bf16) | agg(NN*32 f32)   ~192.6 MB
    // cur/bsum alias agg during the CSR phase (agg zeroed after fill).
    int* offs = (int*)d_ws;
    uint2* emeta = (uint2*)(offs + NN + 8);
    bf16_t* xtf = (bf16_t*)(emeta + NE);
    bf16_t* wtf1 = xtf + (size_t)NN * DD;
    bf16_t* wtf2 = wtf1 + 9 * 2 * 64 * 8;
    bf16_t* y = wtf2 + 25 * 2 * 64 * 8;
    float* agg = (float*)(y + (size_t)NN * 25 * DD);
    int* cur  = (int*)agg;
    int* bsum = (int*)agg + NN;

    const unsigned gn = (NN + 7) / 8;
    const unsigned gy = (NT + 3) / 4;   // 1563 blocks, 4 tiles each

    // ---- CSR build + sorted packed metadata ----
    zero_int_k<<<gblocks(NN), 256, 0, stream>>>(cur, NN);
    hist_k<<<gblocks(NE), 256, 0, stream>>>(dstp, cur);
    s1_k<<<SCAN_B, 256, 0, stream>>>(cur, offs, bsum);
    s2_k<<<1, 512, 0, stream>>>(bsum);
    s3c_k<<<SCAN_B, 256, 0, stream>>>(offs, bsum, cur);
    fill_k<<<gblocks(NE), 256, 0, stream>>>(dstp, srcp, (const float2*)attr, cur, emeta);

    // ---- weight packs ----
    castw2_k<<<gblocks((9 + 25) * 2 * 64), 256, 0, stream>>>(W1, W2, wtf1, wtf2);

    // ---- layer 1 (ksize=3, K=9): ymm reads f32 x directly ----
    ymm_k<9, true><<<gy, 256, 0, stream>>>(x, (const short8v*)wtf1, (uint2*)y);
    zero_k<<<gblocks((long)NN * DD), 256, 0, stream>>>(agg, (long)NN * DD);  // cur dead now
    edge_sr_k<3><<<NB2, 512, 0, stream>>>(emeta, (const unsigned*)y, agg);
    fin1_k<<<gn, 256, 0, stream>>>(agg, offs, x, root1, bias1, xtf);

    // ---- layer 2 (ksize=5, K=25) ----
    ymm_k<25, false><<<gy, 256, 0, stream>>>(xtf, (const short8v*)wtf2, (uint2*)y);
    edge_sr_k<5><<<NB2, 512, 0, stream>>>(emeta, (const unsigned*)y, agg);

    // ---- fused layer-2 finalize + MLP head ----
    finmlp_k<<<gn, 256, 0, stream>>>(agg, offs, xtf, root2, bias2,
                                     m1w, m1b, m2w, m2b, out);
}